// Round 9
// baseline (136.699 us; speedup 1.0000x reference)
//
#include <hip/hip_runtime.h>

// VectorQuantizer: N=131072 tokens, D=64, K=1024 codes.
// out (f32 concat): [0,8388608) quant, [8388608] loss, [8388609,...) idx.
//
// R19: sched_group_barrier-pinned MFMA/VALU interleave + e2 prefetch.
// R18 post-mortem: asymmetric persistent setprio = exact null. Seven
// schedules at 68-70us; MFMA-pipe time invariant ~21us, VALU ~26us, wall ~=
// serialized sum. Cross-wave mechanisms (occupancy/prefetch-depth/priority)
// all failed -> revised theory: hipcc clusters the 12 MFMAs and the UPD
// VALU into disjoint blocks (its scheduler prefers clustering; R17's
// acc-dbuf only gave LICENSE to interleave, VALUBusy 34->39 but wall flat).
// With disjoint clusters every wave alternates pipes; identical waves =>
// the SIMD's matrix and vector pipes alternate instead of co-running.
// R19 forces emitted-order interleave with sched_group_barrier (T19, the
// CK-fmha pattern; this kernel has the fat VALU phase that regime needs):
// MMU fuses MFMA(tile t+1) with UPD(tile t): 6 MFMA pairs each followed by
// 2 UPD elements, pinned SGB(MFMA,2);SGB(VALU,10). Plus: per-tile e2 LDS
// read (~120cyc) hoisted one tile ahead into rotating regs e2A/e2B.
// Scheduling-only changes: expressions, element independence, and
// ascending-nt order preserved -> bit-identical results.
//
// Everything else verbatim R17: 32 tok/wave, grid 1024x256,
// launch_bounds(256,2), 1-deep b prefetch, acc double-buffer, atomicAdd
// loss fusion, 2 launches. Distance math bit-identical to R4-R18: fp16
// split-product MFMA (hi*hi+lo*hi+hi*lo) in the same per-accumulator
// order, np8 x2/e2, s=fma(-2,dot,x2v+e2v), ascending-k strict-< first-min,
// butterfly epilogue, bitwise quant copy.

#define KC 1024
#define DD 64
#define NTOK (32 * 4096)
#define QUANT_ELEMS ((size_t)NTOK * DD)        // 8388608
#define LOSS_OFF QUANT_ELEMS
#define IDX_OFF (QUANT_ELEMS + 1)

// ws float-word offsets (layout identical to R10/R12)
#define WS_E2 0                      // 1024 f32
#define WS_BFRAG_F 2048              // 16384 f16x8 = 65536 f32 words

#define MAIN_BLOCKS (NTOK / 128)     // 1024 blocks, 128 tokens each

typedef _Float16 f16x8 __attribute__((ext_vector_type(8)));
typedef float f32x4 __attribute__((ext_vector_type(4)));

#define SGB __builtin_amdgcn_sched_group_barrier
#define MFMA_F16 __builtin_amdgcn_mfma_f32_16x16x32_f16

__device__ __forceinline__ unsigned int sortable_bits(float f) {
  unsigned int b = __float_as_uint(f);
  return b ^ (unsigned int)(((int)b >> 31) | 0x80000000);
}

__device__ __forceinline__ float unsortable_bits(unsigned int u) {
  unsigned int fb = (u & 0x80000000u) ? (u ^ 0x80000000u) : ~u;
  return __uint_as_float(fb);
}

// np pairwise-8 sum of squares of a 64-float row (bit-identical to R10)
__device__ __forceinline__ float row_sumsq_np8(const float* p) {
  float r[8];
#pragma unroll
  for (int j = 0; j < 8; ++j) r[j] = p[j] * p[j];
#pragma unroll
  for (int i = 1; i < 8; ++i)
#pragma unroll
    for (int j = 0; j < 8; ++j) {
      float v = p[i * 8 + j];
      r[j] += v * v;
    }
  return ((r[0] + r[1]) + (r[2] + r[3])) + ((r[4] + r[5]) + (r[6] + r[7]));
}

// blocks [0,64): B-frag build; [64,68): e2 table (verbatim R10/R12)
// + block 64 tid 0 zeroes the loss accumulator for this iteration.
__global__ void vq_setup(const float* __restrict__ emb,
                         float* __restrict__ ws,
                         float* __restrict__ out) {
  const int b = blockIdx.x;
  const int tid = threadIdx.x;
  if (b < 64) {
    const int nt = b;                  // global tile 0..63 (16 codes each)
    const int f = tid >> 6;            // 0..3: plane(hi/lo) x kstep
    const int lane = tid & 63;
    const int plane = f >> 1, ks = f & 1;
    const int n = nt * 16 + (lane & 15);
    const int kb = ks * 32 + ((lane >> 4) & 3) * 8;
    const float* ep = emb + (size_t)n * DD + kb;
    f16x8 o;
#pragma unroll
    for (int j = 0; j < 8; ++j) {
      float v = ep[j];
      _Float16 h = (_Float16)v;
      o[j] = (plane == 0) ? h : (_Float16)(v - (float)h);
    }
    ((f16x8*)(ws + WS_BFRAG_F))[(nt * 4 + f) * 64 + lane] = o;
  } else {
    const int k = (b - 64) * 256 + tid;  // 0..1023
    ws[WS_E2 + k] = row_sumsq_np8(emb + (size_t)k * DD);
    if (b == 64 && tid == 0) out[LOSS_OFF] = 0.0f;
  }
}

__launch_bounds__(256, 2)
__global__ void vq_main(const float* __restrict__ x_in,
                        const float* __restrict__ emb,
                        const float* __restrict__ ws_ro,
                        float* __restrict__ out) {
  const int tid = threadIdx.x;
  const int wave = tid >> 6, lane = tid & 63;
  const int quad = lane >> 4, l16 = lane & 15;
  const int blockTok = blockIdx.x * 128;
  const int tokBase = blockTok + wave * 32;  // 32 tokens per wave

  __shared__ float E2s[KC];    // 4 KB
  __shared__ float x2s[128];   // per-block token x2
  __shared__ float wsum[4];

  // Stage e2 table to LDS; x2: one row per thread for tid<128
  // (bit-identical np8 -- value depends only on row data, not producer).
#pragma unroll
  for (int i = 0; i < 4; ++i)
    E2s[i * 256 + tid] = ws_ro[WS_E2 + i * 256 + tid];
  if (tid < 128)
    x2s[tid] = row_sumsq_np8(x_in + (size_t)(blockTok + tid) * DD);

  // A fragments: 2 m-sets of 16 tokens; x split into fp16 hi/lo planes.
  f16x8 ah[2][2], al[2][2];
#pragma unroll
  for (int ms = 0; ms < 2; ++ms) {
    const float* xr = x_in + (size_t)(tokBase + ms * 16 + l16) * DD;
#pragma unroll
    for (int ks = 0; ks < 2; ++ks) {
      const float4* p4 = (const float4*)(xr + ks * 32 + quad * 8);
      float4 v0 = p4[0], v1 = p4[1];
      float vv[8] = {v0.x, v0.y, v0.z, v0.w, v1.x, v1.y, v1.z, v1.w};
#pragma unroll
      for (int j = 0; j < 8; ++j) {
        _Float16 h = (_Float16)vv[j];
        ah[ms][ks][j] = h;
        al[ms][ks][j] = (_Float16)(vv[j] - (float)h);
      }
    }
  }

  float best[2][4];
  int bidx[2][4];
#pragma unroll
  for (int ms = 0; ms < 2; ++ms)
#pragma unroll
    for (int r = 0; r < 4; ++r) { best[ms][r] = 3.402823466e38f; bidx[ms][r] = 0; }

  __syncthreads();  // E2s + x2s ready -- the ONLY barrier before epilogue

  // x2 for this lane's C rows: token = tokBase + ms*16 + quad*4 + r
  float x2v[2][4];
#pragma unroll
  for (int ms = 0; ms < 2; ++ms)
#pragma unroll
    for (int r = 0; r < 4; ++r)
      x2v[ms][r] = x2s[wave * 32 + ms * 16 + quad * 4 + r];

  const f16x8* bws = (const f16x8*)(ws_ro + WS_BFRAG_F);

  // One UPD element (ms,r): expression byte-identical to R17's UPD.
  // Elements are independent slots; only ascending-nt per slot matters.
#define UPD1(accU, ms, r, ncur, e2v)                                        \
  {                                                                         \
    float s_ = __builtin_fmaf(-2.0f, accU[ms][r], x2v[ms][r] + (e2v));      \
    if (s_ < best[ms][r]) { best[ms][r] = s_; bidx[ms][r] = (ncur); }       \
  }

  // Plain MM (prologue tile 0 only): 12 MFMA, order identical to R4-R18.
  auto MM = [&](const f16x8 (&bf)[4], f32x4 (&acc)[2]) {
#pragma unroll
    for (int ms = 0; ms < 2; ++ms) acc[ms] = (f32x4){0.f, 0.f, 0.f, 0.f};
#pragma unroll
    for (int ms = 0; ms < 2; ++ms)
      acc[ms] = MFMA_F16(ah[ms][0], bf[0], acc[ms], 0, 0, 0);
#pragma unroll
    for (int ms = 0; ms < 2; ++ms)
      acc[ms] = MFMA_F16(ah[ms][1], bf[1], acc[ms], 0, 0, 0);
#pragma unroll
    for (int ms = 0; ms < 2; ++ms)
      acc[ms] = MFMA_F16(al[ms][0], bf[0], acc[ms], 0, 0, 0);
#pragma unroll
    for (int ms = 0; ms < 2; ++ms)
      acc[ms] = MFMA_F16(al[ms][1], bf[1], acc[ms], 0, 0, 0);
#pragma unroll
    for (int ms = 0; ms < 2; ++ms)
      acc[ms] = MFMA_F16(ah[ms][0], bf[2], acc[ms], 0, 0, 0);
#pragma unroll
    for (int ms = 0; ms < 2; ++ms)
      acc[ms] = MFMA_F16(ah[ms][1], bf[3], acc[ms], 0, 0, 0);
  };

  // MMU: MFMA for the NEXT tile (into acc) interleaved with UPD of the
  // PREVIOUS tile (from accU), pinned by sched_group_barrier so the
  // emitted stream is MFMA2/VALU10/MFMA2/... (matrix pipe fed while the
  // VALU retires the previous tile's min-update). Same MFMA order, same
  // UPD expressions -> bit-identical.
  auto MMU = [&](const f16x8 (&bf)[4], f32x4 (&acc)[2],
                 int ntU, const f32x4 (&accU)[2], float e2v) {
    const int ncur = ntU * 16 + l16;
#pragma unroll
    for (int ms = 0; ms < 2; ++ms) acc[ms] = (f32x4){0.f, 0.f, 0.f, 0.f};
    // pair 1: hi*hi k0
    acc[0] = MFMA_F16(ah[0][0], bf[0], acc[0], 0, 0, 0);
    acc[1] = MFMA_F16(ah[1][0], bf[0], acc[1], 0, 0, 0);
    UPD1(accU, 0, 0, ncur, e2v)
    UPD1(accU, 0, 1, ncur, e2v)
    SGB(0x8, 2, 0); SGB(0x2, 10, 0);
    // pair 2: hi*hi k1
    acc[0] = MFMA_F16(ah[0][1], bf[1], acc[0], 0, 0, 0);
    acc[1] = MFMA_F16(ah[1][1], bf[1], acc[1], 0, 0, 0);
    UPD1(accU, 0, 2, ncur, e2v)
    UPD1(accU, 0, 3, ncur, e2v)
    SGB(0x8, 2, 0); SGB(0x2, 10, 0);
    // pair 3: lo*hi k0
    acc[0] = MFMA_F16(al[0][0], bf[0], acc[0], 0, 0, 0);
    acc[1] = MFMA_F16(al[1][0], bf[0], acc[1], 0, 0, 0);
    UPD1(accU, 1, 0, ncur, e2v)
    UPD1(accU, 1, 1, ncur, e2v)
    SGB(0x8, 2, 0); SGB(0x2, 10, 0);
    // pair 4: lo*hi k1
    acc[0] = MFMA_F16(al[0][1], bf[1], acc[0], 0, 0, 0);
    acc[1] = MFMA_F16(al[1][1], bf[1], acc[1], 0, 0, 0);
    UPD1(accU, 1, 2, ncur, e2v)
    UPD1(accU, 1, 3, ncur, e2v)
    SGB(0x8, 2, 0); SGB(0x2, 10, 0);
    // pair 5: hi*lo k0
    acc[0] = MFMA_F16(ah[0][0], bf[2], acc[0], 0, 0, 0);
    acc[1] = MFMA_F16(ah[1][0], bf[2], acc[1], 0, 0, 0);
    SGB(0x8, 2, 0);
    // pair 6: hi*lo k1
    acc[0] = MFMA_F16(ah[0][1], bf[3], acc[0], 0, 0, 0);
    acc[1] = MFMA_F16(ah[1][1], bf[3], acc[1], 0, 0, 0);
    SGB(0x8, 2, 0);
  };

  // Barrier-free main loop: 64 code-tiles, 1-deep b prefetch, acc dbuf,
  // e2 prefetched one tile ahead into rotating regs (off the UPD critical
  // path; same value, same adds).
  f16x8 bA[4], bB[4];
#pragma unroll
  for (int i = 0; i < 4; ++i) bA[i] = bws[(0 * 4 + i) * 64 + lane];
#pragma unroll
  for (int i = 0; i < 4; ++i) bB[i] = bws[(1 * 4 + i) * 64 + lane];

  f32x4 accA[2], accB[2];
  float e2A = E2s[l16];            // e2 for tile 0
  MM(bA, accA);                    // tile 0
  float e2B = E2s[16 + l16];       // e2 for tile 1

  for (int nt = 0; nt <= 58; nt += 2) {
#pragma unroll
    for (int i = 0; i < 4; ++i) bA[i] = bws[((nt + 2) * 4 + i) * 64 + lane];
    MMU(bB, accB, nt + 0, accA, e2A);         // compute tile nt+1, UPD nt
    e2A = E2s[(nt + 2) * 16 + l16];           // e2 for tile nt+2
#pragma unroll
    for (int i = 0; i < 4; ++i) bB[i] = bws[((nt + 3) * 4 + i) * 64 + lane];
    MMU(bA, accA, nt + 1, accB, e2B);         // compute tile nt+2, UPD nt+1
    e2B = E2s[(nt + 3) * 16 + l16];           // e2 for tile nt+3
  }
  // Exit: MM done through tile 60 (accA), UPD through 59; bB = tile 61;
  // e2A = E2s[60], e2B = E2s[61].
#pragma unroll
  for (int i = 0; i < 4; ++i) bA[i] = bws[(62 * 4 + i) * 64 + lane];
  MMU(bB, accB, 60, accA, e2A);               // tile 61, UPD 60
  e2A = E2s[62 * 16 + l16];
#pragma unroll
  for (int i = 0; i < 4; ++i) bB[i] = bws[(63 * 4 + i) * 64 + lane];
  MMU(bA, accA, 61, accB, e2B);               // tile 62, UPD 61
  e2B = E2s[63 * 16 + l16];
  MMU(bB, accB, 62, accA, e2A);               // tile 63, UPD 62
  {                                           // UPD 63 (plain)
    const int ncur = 63 * 16 + l16;
#pragma unroll
    for (int ms = 0; ms < 2; ++ms)
#pragma unroll
      for (int r = 0; r < 4; ++r) UPD1(accB, ms, r, ncur, e2B)
  }

  // Butterfly min across each quad's 16 lanes -> ALL lanes hold the winner.
  unsigned long long key[2][4];
#pragma unroll
  for (int ms = 0; ms < 2; ++ms)
#pragma unroll
    for (int r = 0; r < 4; ++r) {
      unsigned long long k =
          ((unsigned long long)sortable_bits(best[ms][r]) << 32) |
          (unsigned int)bidx[ms][r];
#pragma unroll
      for (int m = 1; m < 16; m <<= 1) {
        unsigned long long o = __shfl_xor(k, m);
        k = o < k ? o : k;
      }
      key[ms][r] = k;
    }

  // Fused epilogue: idx store (quad lane 0), quant gather+store (all lanes),
  // loss partial decoded from keys.
  float qsum = 0.0f;
#pragma unroll
  for (int ms = 0; ms < 2; ++ms)
#pragma unroll
    for (int r = 0; r < 4; ++r) {
      const int token = tokBase + ms * 16 + quad * 4 + r;
      const int widx = (int)(unsigned int)key[ms][r];
      if (l16 == 0) out[IDX_OFF + (size_t)token] = (float)widx;
      // 16 lanes x float4 = the winning 256B row, bitwise copy
      const float4 v = ((const float4*)(emb + (size_t)widx * DD))[l16];
      ((float4*)(out + (size_t)token * DD))[l16] = v;
      qsum += unsortable_bits((unsigned int)(key[ms][r] >> 32));
    }

  // qsum identical across a quad's 16 lanes; sum the 4 quads, then 4 waves,
  // then atomicAdd the scaled partial into the loss cell (zeroed by setup).
  float tot = __shfl(qsum, 0) + __shfl(qsum, 16) +
              __shfl(qsum, 32) + __shfl(qsum, 48);
  if (lane == 0) wsum[wave] = tot;
  __syncthreads();
  if (tid == 0) {
    // 1.25f / 2^23 is exactly representable; one rounding per block.
    const float scale = 1.25f / (float)QUANT_ELEMS;
    atomicAdd(&out[LOSS_OFF], ((wsum[0] + wsum[1]) + (wsum[2] + wsum[3])) * scale);
  }
}

extern "C" void kernel_launch(void* const* d_in, const int* in_sizes, int n_in,
                              void* d_out, int out_size, void* d_ws, size_t ws_size,
                              hipStream_t stream) {
  const float* x = (const float*)d_in[0];
  const float* emb = (const float*)d_in[1];
  float* out = (float*)d_out;
  float* ws = (float*)d_ws;

  vq_setup<<<68, 256, 0, stream>>>(emb, ws, out);
  vq_main<<<MAIN_BLOCKS, 256, 0, stream>>>(x, emb, ws, out);
}